// Round 10
// baseline (189.456 us; speedup 1.0000x reference)
//
#include <hip/hip_runtime.h>

typedef unsigned short u16;
typedef unsigned int u32;
typedef __attribute__((ext_vector_type(8))) short short8;
typedef __attribute__((ext_vector_type(8))) _Float16 half8;
typedef __attribute__((ext_vector_type(4))) float f32x4;
typedef __attribute__((ext_vector_type(16))) float f32x16;
typedef __attribute__((ext_vector_type(4))) u32 u32x4;

#define S_LEN 2048
#define EDIM  1024
#define DK    64
#define NHEAD 16
// softmax scale 1/8 folded with log2(e) into the Q projection:
#define QSCALE 0.1803368801111f

__device__ inline u16 f2bf(float f) {
    u32 u = __builtin_bit_cast(u32, f);
    u += 0x7fffu + ((u >> 16) & 1u);   // RNE
    return (u16)(u >> 16);
}
__device__ inline u16 f2h(float f) {   // fp32 -> fp16 bits (RNE)
    _Float16 h = (_Float16)f;
    return __builtin_bit_cast(u16, h);
}

#define ASYNC16(gp, lp)                                                        \
    __builtin_amdgcn_global_load_lds(                                          \
        (const __attribute__((address_space(1))) u32*)(gp),                    \
        (__attribute__((address_space(3))) u32*)(lp), 16, 0, 0)

// ---------------------------------------------------------------------------
// Fused fp32->bf16 converts: segment 0 = x (4M els), 1..3 = Wq/Wk/Wv (1M each)
// ---------------------------------------------------------------------------
__global__ __launch_bounds__(256)
void conv_all(const float* __restrict__ x,  const float* __restrict__ Wq,
              const float* __restrict__ Wk, const float* __restrict__ Wv,
              u16* __restrict__ xb, u16* __restrict__ Wb /*3M contiguous*/) {
    const int blk = blockIdx.x;
    const float* src; u16* dst; int idx;
    if (blk < 4096)      { src = x;  dst = xb;             idx = blk; }
    else if (blk < 5120) { src = Wq; dst = Wb;             idx = blk - 4096; }
    else if (blk < 6144) { src = Wk; dst = Wb + (1 << 20); idx = blk - 5120; }
    else                 { src = Wv; dst = Wb + (2 << 20); idx = blk - 6144; }
    const int i = idx * 1024 + threadIdx.x * 4;
    const float4 v = *(const float4*)(src + i);
    u16 o[4] = { f2bf(v.x), f2bf(v.y), f2bf(v.z), f2bf(v.w) };
    *(ulong1*)(dst + i) = *(ulong1*)o;
}

__global__ __launch_bounds__(256)
void f32_to_bf16(const float* __restrict__ src, u16* __restrict__ dst, int n) {
    const int i = (blockIdx.x * 256 + threadIdx.x) * 4;
    if (i + 3 < n) {
        const float4 v = *(const float4*)(src + i);
        u16 o[4] = { f2bf(v.x), f2bf(v.y), f2bf(v.z), f2bf(v.w) };
        *(ulong1*)(dst + i) = *(ulong1*)o;
    }
}

// ---------------------------------------------------------------------------
// NT GEMM: C[m][n] = sum_k A[m][k]*B[n][k]. Block tile (MT*32) x 128.
// bf16 path: BK=64, XOR-swizzled LDS (slot = piece ^ (row&7)).
// EPI 0 (QKV fused, z selects): z0 -> Q bf16 * QSCALE, z1 -> K bf16,
//   z2 -> V scattered to VT as FP16 with the sigma(j) permutation.
// EPI 2: fp32 row-major.
// BF32 (tight-ws fallback): BK=32, B fp32 staged + converted.
// No min-waves bound: VGPR ~130 -> natural 3 waves/SIMD (3 blocks/CU).
// ---------------------------------------------------------------------------
template<int EPI, bool BF32, int MT>
__global__ __launch_bounds__(256)
void gemm128(const u16* __restrict__ A,
             const void* __restrict__ B0, const void* __restrict__ B1,
             const void* __restrict__ B2,
             u16* __restrict__ C0, u16* __restrict__ C1, u16* __restrict__ C2,
             float* __restrict__ Cf, int M, int N, int K) {
    const void* Bv = B0;
    u16*        Cp = C0;
    float       cscale = (EPI == 0) ? QSCALE : 1.0f;
    if (blockIdx.z == 1) { Bv = B1; Cp = C1; cscale = 1.0f; }
    else if (blockIdx.z == 2) { Bv = B2; Cp = C2; cscale = 1.0f; }

    const int tid  = threadIdx.x;
    const int lane = tid & 63;
    const int w    = tid >> 6;
    const int quad = lane >> 4;
    const int l16  = lane & 15;
    const int wm   = w >> 1;
    const int wn   = w & 1;
    const int m0   = blockIdx.y * (MT * 32);
    const int n0   = blockIdx.x * 128;

    __shared__ u16 lA[MT * 32 * (BF32 ? 32 : 64)];
    __shared__ __align__(16) char lBraw[BF32 ? 128 * 32 * 4 : 128 * 64 * 2];

    f32x4 acc[MT][4] = {};

    if (!BF32) {
        // ---- BK = 64, swizzled ----
        u16* lB = (u16*)lBraw;
        const int rsub  = lane >> 3;           // 0..7
        const int piece = (lane & 7) ^ (rsub & 7);
        for (int k0 = 0; k0 < K; k0 += 64) {
            __syncthreads();
#pragma unroll
            for (int i = 0; i < MT; ++i) {
                const int row = w * (MT * 8) + i * 8 + rsub;
                ASYNC16(A + (size_t)(m0 + row) * K + k0 + piece * 8,
                        &lA[(w * (MT * 8) + i * 8) * 64]);
            }
            const u16* Bp = (const u16*)Bv;
#pragma unroll
            for (int i = 0; i < 4; ++i) {
                const int row = w * 32 + i * 8 + rsub;
                ASYNC16(Bp + (size_t)(n0 + row) * K + k0 + piece * 8,
                        &lB[(w * 32 + i * 8) * 64]);
            }
            __syncthreads();

#pragma unroll
            for (int ks = 0; ks < 2; ++ks) {
                short8 av[MT], bv[4];
#pragma unroll
                for (int t = 0; t < MT; ++t)
                    av[t] = *(const short8*)&lA[(wm * (MT * 16) + t * 16 + l16) * 64 +
                                                (((ks * 4 + quad)) ^ (l16 & 7)) * 8];
#pragma unroll
                for (int t = 0; t < 4; ++t)
                    bv[t] = *(const short8*)&lB[(wn * 64 + t * 16 + l16) * 64 +
                                                (((ks * 4 + quad)) ^ (l16 & 7)) * 8];
#pragma unroll
                for (int mt = 0; mt < MT; ++mt)
#pragma unroll
                    for (int nt = 0; nt < 4; ++nt)
                        acc[mt][nt] = __builtin_amdgcn_mfma_f32_16x16x32_bf16(
                            av[mt], bv[nt], acc[mt][nt], 0, 0, 0);
            }
        }
    } else {
        // ---- legacy BK = 32, B fp32 ----
        for (int k0 = 0; k0 < K; k0 += 32) {
            __syncthreads();
#pragma unroll
            for (int i = 0; i < MT / 2; ++i) {
                const int row = w * (MT * 8) + i * 16 + (lane >> 2);
                const int col = (lane & 3) * 8;
                ASYNC16(A + (size_t)(m0 + row) * K + k0 + col,
                        &lA[(w * (MT * 8) + i * 16) * 32]);
            }
            const float* Bp  = (const float*)Bv;
            float*       lBs = (float*)lBraw;
#pragma unroll
            for (int i = 0; i < 4; ++i) {
                const int row = w * 32 + i * 8 + (lane >> 3);
                const int col = (lane & 7) * 4;
                ASYNC16(Bp + (size_t)(n0 + row) * K + k0 + col,
                        &lBs[(w * 32 + i * 8) * 32]);
            }
            __syncthreads();

            short8 av[MT], bv[4];
#pragma unroll
            for (int t = 0; t < MT; ++t)
                av[t] = *(const short8*)&lA[(wm * (MT * 16) + t * 16 + l16) * 32 + quad * 8];
            const float* lBr = (const float*)lBraw;
#pragma unroll
            for (int t = 0; t < 4; ++t) {
                const float* src = &lBr[(wn * 64 + t * 16 + l16) * 32 + quad * 8];
                const f32x4 x0 = *(const f32x4*)src;
                const f32x4 x1 = *(const f32x4*)(src + 4);
                short8 bq;
#pragma unroll
                for (int j = 0; j < 4; ++j) {
                    bq[j]     = (short)f2bf(x0[j]);
                    bq[4 + j] = (short)f2bf(x1[j]);
                }
                bv[t] = bq;
            }
#pragma unroll
            for (int mt = 0; mt < MT; ++mt)
#pragma unroll
                for (int nt = 0; nt < 4; ++nt)
                    acc[mt][nt] = __builtin_amdgcn_mfma_f32_16x16x32_bf16(
                        av[mt], bv[nt], acc[mt][nt], 0, 0, 0);
        }
    }

    // epilogue: C/D layout col=lane&15, row=quad*4+reg
#pragma unroll
    for (int mt = 0; mt < MT; ++mt)
#pragma unroll
        for (int nt = 0; nt < 4; ++nt) {
            if (EPI == 0 && blockIdx.z == 2) {
                // V -> VT[(b*16+h)*64+d][sigma(s)] as fp16.
                const int col    = n0 + wn * 64 + nt * 16 + l16;
                const int h      = (col >> 6) & 15;
                const int d      = col & 63;
                const int quadsw = ((quad & 1) << 1) | (quad >> 1);
                const int rowb   = m0 + wm * (MT * 16) + mt * 16;  // 16-aligned
                const int b      = rowb >> 11;
                const int s      = (rowb & 2047) + quadsw * 4;
                ushort4 o;
                o.x = f2h(acc[mt][nt][0]);
                o.y = f2h(acc[mt][nt][1]);
                o.z = f2h(acc[mt][nt][2]);
                o.w = f2h(acc[mt][nt][3]);
                *(ushort4*)&Cp[((size_t)(b * 16 + h) * 64 + d) * S_LEN + s] = o;
            } else {
#pragma unroll
                for (int r = 0; r < 4; ++r) {
                    const int row = m0 + wm * (MT * 16) + mt * 16 + quad * 4 + r;
                    const int col = n0 + wn * 64 + nt * 16 + l16;
                    if (EPI == 2)
                        Cf[(size_t)row * N + col] = acc[mt][nt][r];
                    else
                        Cp[(size_t)row * N + col] = f2bf(acc[mt][nt][r] * cscale);
                }
            }
        }
}

// ---------------------------------------------------------------------------
// Attention v7: block = (bh, 256-q-tile), 4 waves, EACH WAVE OWNS 64 q-rows
// (two 32-row subsets) -> every aK/bV LDS read feeds TWO MFMAs, halving LDS
// traffic per unit work (R9 analysis: LDS was the binding floor at 17.5 µs).
// 256 blocks = 1 block/CU -> VGPR pressure free (4 waves vs 512-VGPR budget).
// attn6 machinery retained: global_load_lds staging (XOR-swizzled), double
// buffer, one barrier/iter with post-barrier prefetch, unstabilized exp2,
// cvt_pkrtz fp16 P, sigma-permuted VT (no cross-lane exchange), f16 PV.
// ---------------------------------------------------------------------------
__global__ __launch_bounds__(256)
void attn7(const u16* __restrict__ Qg, const u16* __restrict__ Kg,
           const u16* __restrict__ VTg /*fp16, sigma-permuted*/,
           const float* __restrict__ qp, u16* __restrict__ Mg) {
    const int tid  = threadIdx.x;
    const int lane = tid & 63;
    const int w    = tid >> 6;
    const int l32  = lane & 31;
    const int hi   = lane >> 5;
    const int bh   = blockIdx.x;
    const int b    = bh >> 4;
    const int h    = bh & 15;
    const int q0   = blockIdx.y * 256;

    __shared__ u16 lK[2][128 * 64];   // [buf][row j][slot*8] bf16, swizzled
    __shared__ u16 lV[2][64 * 128];   // [buf][row d][slot*8] fp16, swizzled

    const float qc = cosf(qp[0] + qp[1]);

    // Q as MFMA B-operand, two 32-row subsets per wave:
    // m = q0 + w*64 + qs*32 + l32, k = kk*16 + hi*8 + i
    short8 bq[2][4];
#pragma unroll
    for (int qs = 0; qs < 2; ++qs) {
        const u16* qrow = Qg +
            (size_t)(b * S_LEN + q0 + w * 64 + qs * 32 + l32) * EDIM +
            h * DK + hi * 8;
#pragma unroll
        for (int kk = 0; kk < 4; ++kk)
            bq[qs][kk] = *(const short8*)(qrow + kk * 16);
    }

    const int kpiece = (lane & 7) ^ ((lane >> 3) & 7);
    const u16* kgbase = Kg + (size_t)b * S_LEN * EDIM + h * DK + kpiece * 8 +
                        (size_t)(w * 32 + (lane >> 3)) * EDIM;
    const u16* vgbase = VTg + (size_t)(bh * DK + w * 16 + (lane >> 4)) * S_LEN;

    f32x16 oacc[2][2] = {};   // [qs][dt]; lane = d, regs = m (C layout)
    float  la[2][2] = {};     // [qs][chain] li partials

#define STAGE(BUF, J0)                                                         \
    {                                                                          \
        _Pragma("unroll")                                                      \
        for (int i = 0; i < 4; ++i)                                            \
            ASYNC16(kgbase + (size_t)(J0 + i * 8) * EDIM,                      \
                    &lK[BUF][(w * 32 + i * 8) * 64]);                          \
        _Pragma("unroll")                                                      \
        for (int i = 0; i < 4; ++i) {                                          \
            const int pv = (lane & 15) ^ ((w * 16 + i * 4 + (lane >> 4)) & 15);\
            ASYNC16(vgbase + (size_t)(i * 4) * S_LEN + (J0) + pv * 8,          \
                    &lV[BUF][(w * 16 + i * 4) * 128]);                         \
        }                                                                      \
    }

    STAGE(0, 0)

    for (int t = 0; t < S_LEN / 128; ++t) {
        __syncthreads();   // drains tile t's staging (issued 1 compute-phase ago)
        if (t + 1 < S_LEN / 128)
            STAGE((t + 1) & 1, (t + 1) * 128)
        const u16* bK  = lK[t & 1];
        const u16* bVb = lV[t & 1];

#pragma unroll
        for (int jt = 0; jt < 4; ++jt) {
            const int jr = jt * 32 + l32;
            // S^T tiles for both q-subsets; each aK read feeds 2 MFMAs
            f32x16 sT0 = {}, sT1 = {};
#pragma unroll
            for (int kk = 0; kk < 4; ++kk) {
                const short8 aK = *(const short8*)
                    &bK[jr * 64 + ((kk * 2 + hi) ^ (l32 & 7)) * 8];
                sT0 = __builtin_amdgcn_mfma_f32_32x32x16_bf16(aK, bq[0][kk], sT0, 0, 0, 0);
                sT1 = __builtin_amdgcn_mfma_f32_32x32x16_bf16(aK, bq[1][kk], sT1, 0, 0, 0);
            }
            float e[2][16];
#pragma unroll
            for (int r = 0; r < 16; ++r) {
                e[0][r] = __builtin_amdgcn_exp2f(sT0[r]);
                e[1][r] = __builtin_amdgcn_exp2f(sT1[r]);
                la[0][r & 1] += e[0][r];
                la[1][r & 1] += e[1][r];
            }
#pragma unroll
            for (int s = 0; s < 2; ++s) {
                const int ks = jt * 2 + s;
                // bV reads shared across both q-subsets
                half8 bV[2];
#pragma unroll
                for (int dt = 0; dt < 2; ++dt)
                    bV[dt] = *(const half8*)
                        &bVb[(dt * 32 + l32) * 128 + ((ks * 2 + hi) ^ (l32 & 15)) * 8];
#pragma unroll
                for (int qs = 0; qs < 2; ++qs) {
                    u32x4 tt;
                    tt[0] = __builtin_bit_cast(u32,
                        __builtin_amdgcn_cvt_pkrtz(e[qs][8 * s + 0], e[qs][8 * s + 1]));
                    tt[1] = __builtin_bit_cast(u32,
                        __builtin_amdgcn_cvt_pkrtz(e[qs][8 * s + 2], e[qs][8 * s + 3]));
                    tt[2] = __builtin_bit_cast(u32,
                        __builtin_amdgcn_cvt_pkrtz(e[qs][8 * s + 4], e[qs][8 * s + 5]));
                    tt[3] = __builtin_bit_cast(u32,
                        __builtin_amdgcn_cvt_pkrtz(e[qs][8 * s + 6], e[qs][8 * s + 7]));
                    const half8 aP = __builtin_bit_cast(half8, tt);
#pragma unroll
                    for (int dt = 0; dt < 2; ++dt)
                        oacc[qs][dt] = __builtin_amdgcn_mfma_f32_32x32x16_f16(
                            aP, bV[dt], oacc[qs][dt], 0, 0, 0);
                }
            }
        }
    }
#undef STAGE

    // epilogue per q-subset: li (lane = m) -> merge hi halves; normalize
#pragma unroll
    for (int qs = 0; qs < 2; ++qs) {
        float li = la[qs][0] + la[qs][1];
        li += __shfl_xor(li, 32, 64);
        const float inv = 1.f / li;
#pragma unroll
        for (int r = 0; r < 16; ++r) {
            const int ml   = (r & 3) + 8 * (r >> 2) + 4 * hi;
            const float im = __shfl(inv, ml, 64);
            const int sg   = q0 + w * 64 + qs * 32 + ml;
#pragma unroll
            for (int dt = 0; dt < 2; ++dt) {
                const int d = dt * 32 + l32;
                float val = oacc[qs][dt][r] * im;
                if (d < 4) val += qc;
                Mg[(size_t)(b * S_LEN + sg) * EDIM + h * DK + d] = f2bf(val);
            }
        }
    }
}

// ---------------------------------------------------------------------------
// Workspace: fast path (ws >= 22 MB): xb[0,8M) + VT[8M,16M) + Wqkv[16M,22M);
//   Wo converted into the Wq slot after the QKV GEMM (stream-ordered).
// tight path (ws >= 16 MB): xb + VT only; weights read fp32 inside the GEMM.
// Q,K (bf16, 8 MB each) live in d_out (16 MB fp32), dead before the final
// projection overwrites it.  Host branch depends only on ws_size (constant).
// ---------------------------------------------------------------------------
extern "C" void kernel_launch(void* const* d_in, const int* in_sizes, int n_in,
                              void* d_out, int out_size, void* d_ws, size_t ws_size,
                              hipStream_t stream) {
    const float* x  = (const float*)d_in[0];
    const float* Wq = (const float*)d_in[1];
    const float* Wk = (const float*)d_in[2];
    const float* Wv = (const float*)d_in[3];
    const float* Wo = (const float*)d_in[4];
    const float* qp = (const float*)d_in[5];

    const size_t BUF  = (size_t)2 * S_LEN * EDIM;   // 4M elements
    const size_t WBUF = (size_t)EDIM * EDIM;        // 1M elements

    u16* Q  = (u16*)d_out;
    u16* Kb = Q + BUF;

    u16* ws    = (u16*)d_ws;
    u16* xb    = ws;                 // dead after QKV; mixed reuses it
    u16* mixed = xb;
    u16* VT    = ws + BUF;           // fp16 V^T (sigma-permuted)
    u16* Wqb   = ws + 2 * BUF;       // fast path only: Wq,Wk,Wv contiguous
    u16* Wkb   = Wqb + WBUF;
    u16* Wvb   = Wkb + WBUF;
    u16* Wob   = Wqb;                // reuses Wq slot after QKV GEMM
    float* out = (float*)d_out;

    const int M = 2 * S_LEN, N = EDIM, Kd = EDIM;
    const dim3 gqkv(N / 128, M / 128, 3);           // 768 blocks (3/CU)
    const dim3 gfin(N / 128, M / 128, 1);           // 256 blocks MT=4 (1/CU)
    const dim3 gattn(2 * NHEAD, S_LEN / 256, 1);    // 256 blocks (1/CU)
    const bool fast = ws_size >= (size_t)(2 * BUF + 3 * WBUF) * sizeof(u16);

    if (fast) {
        conv_all<<<7168, 256, 0, stream>>>(x, Wq, Wk, Wv, xb, Wqb);
        gemm128<0, false, 4><<<gqkv, 256, 0, stream>>>(
            xb, Wqb, Wkb, Wvb, Q, Kb, VT, nullptr, M, N, Kd);
        f32_to_bf16<<<(int)(WBUF / 1024), 256, 0, stream>>>(Wo, Wob, (int)WBUF);
        attn7<<<gattn, 256, 0, stream>>>(Q, Kb, VT, qp, mixed);
        gemm128<2, false, 4><<<gfin, 256, 0, stream>>>(
            mixed, Wob, Wob, Wob, nullptr, nullptr, nullptr, out, M, N, Kd);
    } else {
        f32_to_bf16<<<(int)(BUF / 1024), 256, 0, stream>>>(x, xb, (int)BUF);
        gemm128<0, true, 4><<<gqkv, 256, 0, stream>>>(
            xb, Wq, Wk, Wv, Q, Kb, VT, nullptr, M, N, Kd);
        attn7<<<gattn, 256, 0, stream>>>(Q, Kb, VT, qp, mixed);
        gemm128<2, true, 4><<<gfin, 256, 0, stream>>>(
            mixed, Wo, Wo, Wo, nullptr, nullptr, nullptr, out, M, N, Kd);
    }
}